// Round 4
// baseline (344.732 us; speedup 1.0000x reference)
//
#include <hip/hip_runtime.h>
#include <hip/hip_bf16.h>

#define B_ 2
#define T_ 2048
#define C_ 1024
#define H_ 16
#define D_ 64
#define M1 4096
#define N1 3072
#define K_ 1024

typedef __attribute__((ext_vector_type(8))) __bf16 bf16x8;
typedef __attribute__((ext_vector_type(4))) float f32x4;
typedef __attribute__((ext_vector_type(8))) unsigned short ushort8_t;
typedef __attribute__((ext_vector_type(4))) unsigned short ushort4_t;

static __device__ __forceinline__ unsigned short f2bf(float f) {
    unsigned int u = __builtin_bit_cast(unsigned int, f);
    u += 0x7fffu + ((u >> 16) & 1u);
    return (unsigned short)(u >> 16);
}

// hardware cvt (RNE) — hot path
static __device__ __forceinline__ unsigned short f2bf_hw(float f) {
    return __builtin_bit_cast(unsigned short, (__bf16)f);
}

static __device__ __forceinline__ bf16x8 bload(const unsigned short* p) {
    return __builtin_bit_cast(bf16x8, *(const ushort8_t*)p);
}

// ---- DPP 16-lane reductions (VALU-rate, no LDS pipe) ----
template <int CTRL>
static __device__ __forceinline__ float dpp_mov(float v) {
    return __builtin_bit_cast(float,
        __builtin_amdgcn_update_dpp(0, __builtin_bit_cast(int, v), CTRL, 0xF, 0xF, true));
}
static __device__ __forceinline__ float dpp_fmax16(float v) {
    v = fmaxf(v, dpp_mov<0xB1>(v));   // quad_perm (1,0,3,2)  : xor 1
    v = fmaxf(v, dpp_mov<0x4E>(v));   // quad_perm (2,3,0,1)  : xor 2
    v = fmaxf(v, dpp_mov<0x141>(v));  // row_half_mirror
    v = fmaxf(v, dpp_mov<0x140>(v));  // row_mirror
    return v;
}
static __device__ __forceinline__ float dpp_fadd16(float v) {
    v += dpp_mov<0xB1>(v);
    v += dpp_mov<0x4E>(v);
    v += dpp_mov<0x141>(v);
    v += dpp_mov<0x140>(v);
    return v;
}

// ---------------- cast x -> bf16 ----------------
__global__ void cast_x_kernel(const float* __restrict__ in,
                              unsigned short* __restrict__ out, int n4) {
    int idx = blockIdx.x * blockDim.x + threadIdx.x;
    int stride = gridDim.x * blockDim.x;
    for (int i = idx; i < n4; i += stride) {
        float4 v = ((const float4*)in)[i];
        ushort4_t o;
        o.x = f2bf(v.x); o.y = f2bf(v.y); o.z = f2bf(v.z); o.w = f2bf(v.w);
        ((ushort4_t*)out)[i] = o;
    }
}

// ------------- transpose f32[K][N] -> bf16[N][K] -------------
__global__ void transpose_cast_kernel(const float* __restrict__ in,
                                      unsigned short* __restrict__ out,
                                      int K, int N) {
    __shared__ float tile[32][33];
    int tx = threadIdx.x & 31;
    int ty = threadIdx.x >> 5;   // 0..7
    int n0 = blockIdx.x * 32;
    int k0 = blockIdx.y * 32;
#pragma unroll
    for (int rr = 0; rr < 32; rr += 8)
        tile[ty + rr][tx] = in[(size_t)(k0 + ty + rr) * N + n0 + tx];
    __syncthreads();
#pragma unroll
    for (int rr = 0; rr < 32; rr += 8)
        out[(size_t)(n0 + ty + rr) * K + k0 + tx] = f2bf(tile[tx][ty + rr]);
}

// ---------------- GEMM1: qkv = Xb @ Wt1^T + b ----------------
#define BKQ 32
#define LDSS 48   // padded row stride (elements); 96B keeps 16B alignment

__global__ __launch_bounds__(256)
void gemm_qkv_kernel(const unsigned short* __restrict__ A,   // [4096][1024] bf16
                     const unsigned short* __restrict__ Bt,  // [3072][1024] bf16 (w_attn^T)
                     const float* __restrict__ bias,         // [3072]
                     unsigned short* __restrict__ Qo,        // [BH][T][D] (pre-scaled)
                     unsigned short* __restrict__ Ko,        // [BH][T][D]
                     unsigned short* __restrict__ Vt)        // [BH][D][T]
{
    __shared__ unsigned short As[128][LDSS];
    __shared__ unsigned short Bs[128][LDSS];
    const int tid = threadIdx.x;
    const int lane = tid & 63;
    const int wave = tid >> 6;
    const int g = lane >> 4, cl = lane & 15;
    const int wr = (wave >> 1) * 64, wc = (wave & 1) * 64;
    const int row0 = blockIdx.x * 128;
    const int col0 = blockIdx.y * 128;

    f32x4 acc[4][4];
#pragma unroll
    for (int m = 0; m < 4; ++m)
#pragma unroll
        for (int n = 0; n < 4; ++n)
            acc[m][n] = (f32x4){0.f, 0.f, 0.f, 0.f};

    for (int k0 = 0; k0 < K_; k0 += BKQ) {
#pragma unroll
        for (int s = 0; s < 2; ++s) {
            int chunk = tid + s * 256;         // 512 chunks of 8 bf16
            int r = chunk >> 2;
            int kc = (chunk & 3) * 8;
            *(ushort8_t*)&As[r][kc] =
                *(const ushort8_t*)(A + (size_t)(row0 + r) * K_ + k0 + kc);
            *(ushort8_t*)&Bs[r][kc] =
                *(const ushort8_t*)(Bt + (size_t)(col0 + r) * K_ + k0 + kc);
        }
        __syncthreads();
        bf16x8 af[4], bfv[4];
#pragma unroll
        for (int m = 0; m < 4; ++m)
            af[m] = bload(&As[wr + m * 16 + cl][g * 8]);
#pragma unroll
        for (int n = 0; n < 4; ++n)
            bfv[n] = bload(&Bs[wc + n * 16 + cl][g * 8]);
#pragma unroll
        for (int m = 0; m < 4; ++m)
#pragma unroll
            for (int n = 0; n < 4; ++n)
                acc[m][n] = __builtin_amdgcn_mfma_f32_16x16x32_bf16(
                    af[m], bfv[n], acc[m][n], 0, 0, 0);
        __syncthreads();
    }

    // Q prescale folds 1/sqrt(64) AND log2(e) so attention can use exp2 directly.
    const float QSCALE = 0.125f * 1.44269504088896340736f;
#pragma unroll
    for (int m = 0; m < 4; ++m) {
        int i0 = row0 + wr + m * 16 + g * 4;
#pragma unroll
        for (int n = 0; n < 4; ++n) {
            int j = col0 + wc + n * 16 + cl;
            int which = j >> 10;
            int c = j & 1023;
            int h = c >> 6, d = c & 63;
            float bv = bias[j];
#pragma unroll
            for (int r = 0; r < 4; ++r) {
                int i = i0 + r;
                int b = i >> 11, t = i & 2047;
                size_t bh = (size_t)(b * H_ + h);
                float val = acc[m][n][r] + bv;
                if (which == 0) {
                    Qo[(bh * T_ + t) * D_ + d] = f2bf(val * QSCALE);
                } else if (which == 1) {
                    Ko[(bh * T_ + t) * D_ + d] = f2bf(val);
                } else {
                    Vt[(bh * D_ + d) * T_ + t] = f2bf(val);
                }
            }
        }
    }
}

// ---------------- flash attention (causal) ----------------
// grid: (32 qt, 32 bh) = 1024 blocks -> 4 blocks/CU, 16 waves/CU.
// blockIdx.x -> qt interleaves long/short tiles so each CU's resident set is
// load-balanced. Scores arrive pre-scaled by log2(e): softmax uses exp2.
__global__ __launch_bounds__(256)
void attn_kernel(const unsigned short* __restrict__ Q,   // [BH][T][D], pre-scaled
                 const unsigned short* __restrict__ Kb,  // [BH][T][D]
                 const unsigned short* __restrict__ Vh_, // [BH][D][T]
                 unsigned short* __restrict__ AO)        // [B][T][C] bf16
{
    __shared__ unsigned short Plds[4][2][16][80];
    const int x = blockIdx.x;
    const int qt = (x & 1) ? (31 - (x >> 1)) : (x >> 1);
    const int bh = blockIdx.y;    // 0..31
    const int b = bh >> 4, h = bh & 15;
    const int lane = threadIdx.x & 63;
    const int wave = threadIdx.x >> 6;
    const int g = lane >> 4, cl = lane & 15;
    const int q0 = qt * 64 + wave * 16;

    const unsigned short* Qh = Q + (size_t)bh * T_ * D_;
    const unsigned short* Kh = Kb + (size_t)bh * T_ * D_;
    const unsigned short* Vh = Vh_ + (size_t)bh * D_ * T_;

    bf16x8 qf[2];
#pragma unroll
    for (int c2 = 0; c2 < 2; ++c2)
        qf[c2] = bload(Qh + (size_t)(q0 + cl) * D_ + c2 * 32 + g * 8);

    f32x4 oacc[4];
#pragma unroll
    for (int n = 0; n < 4; ++n) oacc[n] = (f32x4){0.f, 0.f, 0.f, 0.f};
    float mrow[4] = {-INFINITY, -INFINITY, -INFINITY, -INFINITY};
    float lrow[4] = {0.f, 0.f, 0.f, 0.f};

    // QK^T for one 64-wide chunk
    auto qk64 = [&](int kb, f32x4* sacc) {
#pragma unroll
        for (int n = 0; n < 4; ++n) {
            sacc[n] = (f32x4){0.f, 0.f, 0.f, 0.f};
#pragma unroll
            for (int c2 = 0; c2 < 2; ++c2) {
                bf16x8 kf = bload(Kh + (size_t)(kb + n * 16 + cl) * D_ + c2 * 32 + g * 8);
                sacc[n] = __builtin_amdgcn_mfma_f32_16x16x32_bf16(qf[c2], kf, sacc[n], 0, 0, 0);
            }
        }
    };
    // P-transpose via per-wave LDS + PV accumulate for one 64-wide chunk
    auto pv64 = [&](int kb, int buf, float (*p)[4]) {
#pragma unroll
        for (int n = 0; n < 4; ++n)
#pragma unroll
            for (int r = 0; r < 4; ++r)
                Plds[wave][buf][g * 4 + r][n * 16 + cl] = f2bf_hw(p[n][r]);
        bf16x8 pf[2];
#pragma unroll
        for (int c2 = 0; c2 < 2; ++c2)
            pf[c2] = bload(&Plds[wave][buf][cl][c2 * 32 + g * 8]);
#pragma unroll
        for (int n = 0; n < 4; ++n) {
#pragma unroll
            for (int c2 = 0; c2 < 2; ++c2) {
                bf16x8 vf = bload(Vh + (size_t)(n * 16 + cl) * T_ + kb + c2 * 32 + g * 8);
                oacc[n] = __builtin_amdgcn_mfma_f32_16x16x32_bf16(pf[c2], vf, oacc[n], 0, 0, 0);
            }
        }
    };

    int kt = 0;
    // ---- 128-wide unmasked main loop ----
    for (; kt + 2 <= qt; kt += 2) {
        int kb0 = kt * 64, kb1 = kb0 + 64;
        f32x4 s0[4], s1[4];
        qk64(kb0, s0);
        qk64(kb1, s1);
        float p0[4][4], p1[4][4];
#pragma unroll
        for (int r = 0; r < 4; ++r) {
            float vmax = s0[0][r];
#pragma unroll
            for (int n = 1; n < 4; ++n) vmax = fmaxf(vmax, s0[n][r]);
#pragma unroll
            for (int n = 0; n < 4; ++n) vmax = fmaxf(vmax, s1[n][r]);
            vmax = dpp_fmax16(vmax);
            float mn = fmaxf(mrow[r], vmax);
            float alpha = exp2f(mrow[r] - mn);
            float ps = 0.f;
#pragma unroll
            for (int n = 0; n < 4; ++n) { p0[n][r] = exp2f(s0[n][r] - mn); ps += p0[n][r]; }
#pragma unroll
            for (int n = 0; n < 4; ++n) { p1[n][r] = exp2f(s1[n][r] - mn); ps += p1[n][r]; }
            ps = dpp_fadd16(ps);
            lrow[r] = lrow[r] * alpha + ps;
            mrow[r] = mn;
#pragma unroll
            for (int n = 0; n < 4; ++n) oacc[n][r] *= alpha;
        }
        pv64(kb0, 0, p0);
        pv64(kb1, 1, p1);
    }
    // ---- leftover single 64-wide tiles (possibly one unmasked + diagonal) ----
    for (; kt <= qt; ++kt) {
        int kb = kt * 64;
        bool diag = (kt == qt);
        f32x4 s0[4];
        qk64(kb, s0);
        if (diag) {
#pragma unroll
            for (int n = 0; n < 4; ++n) {
                int tk = kb + n * 16 + cl;
#pragma unroll
                for (int r = 0; r < 4; ++r) {
                    int tq = q0 + g * 4 + r;
                    if (tk > tq) s0[n][r] = -INFINITY;
                }
            }
        }
        float p0[4][4];
#pragma unroll
        for (int r = 0; r < 4; ++r) {
            float vmax = s0[0][r];
#pragma unroll
            for (int n = 1; n < 4; ++n) vmax = fmaxf(vmax, s0[n][r]);
            vmax = dpp_fmax16(vmax);
            float mn = fmaxf(mrow[r], vmax);
            float alpha = exp2f(mrow[r] - mn);
            float ps = 0.f;
#pragma unroll
            for (int n = 0; n < 4; ++n) { p0[n][r] = exp2f(s0[n][r] - mn); ps += p0[n][r]; }
            ps = dpp_fadd16(ps);
            lrow[r] = lrow[r] * alpha + ps;
            mrow[r] = mn;
#pragma unroll
            for (int n = 0; n < 4; ++n) oacc[n][r] *= alpha;
        }
        pv64(kb, 0, p0);
    }
    // ---- epilogue ----
#pragma unroll
    for (int r = 0; r < 4; ++r) {
        float inv = 1.f / lrow[r];
        int t = q0 + g * 4 + r;
#pragma unroll
        for (int n = 0; n < 4; ++n)
            AO[((size_t)b * T_ + t) * C_ + h * D_ + n * 16 + cl] =
                f2bf_hw(oacc[n][r] * inv);
    }
}

// ---------------- GEMM2: out = AO @ Wt2^T + b (fp32 out) ----------------
__global__ __launch_bounds__(256)
void gemm_proj_kernel(const unsigned short* __restrict__ A,   // [4096][1024] bf16
                      const unsigned short* __restrict__ Bt,  // [1024][1024] bf16 (w_proj^T)
                      const float* __restrict__ bias,         // [1024]
                      float* __restrict__ out)                // [4096][1024] f32
{
    __shared__ unsigned short As[128][LDSS];
    __shared__ unsigned short Bs[128][LDSS];
    const int tid = threadIdx.x;
    const int lane = tid & 63;
    const int wave = tid >> 6;
    const int g = lane >> 4, cl = lane & 15;
    const int wr = (wave >> 1) * 64, wc = (wave & 1) * 64;
    const int row0 = blockIdx.x * 128;
    const int col0 = blockIdx.y * 128;

    f32x4 acc[4][4];
#pragma unroll
    for (int m = 0; m < 4; ++m)
#pragma unroll
        for (int n = 0; n < 4; ++n)
            acc[m][n] = (f32x4){0.f, 0.f, 0.f, 0.f};

    for (int k0 = 0; k0 < K_; k0 += BKQ) {
#pragma unroll
        for (int s = 0; s < 2; ++s) {
            int chunk = tid + s * 256;
            int r = chunk >> 2;
            int kc = (chunk & 3) * 8;
            *(ushort8_t*)&As[r][kc] =
                *(const ushort8_t*)(A + (size_t)(row0 + r) * K_ + k0 + kc);
            *(ushort8_t*)&Bs[r][kc] =
                *(const ushort8_t*)(Bt + (size_t)(col0 + r) * K_ + k0 + kc);
        }
        __syncthreads();
        bf16x8 af[4], bfv[4];
#pragma unroll
        for (int m = 0; m < 4; ++m)
            af[m] = bload(&As[wr + m * 16 + cl][g * 8]);
#pragma unroll
        for (int n = 0; n < 4; ++n)
            bfv[n] = bload(&Bs[wc + n * 16 + cl][g * 8]);
#pragma unroll
        for (int m = 0; m < 4; ++m)
#pragma unroll
            for (int n = 0; n < 4; ++n)
                acc[m][n] = __builtin_amdgcn_mfma_f32_16x16x32_bf16(
                    af[m], bfv[n], acc[m][n], 0, 0, 0);
        __syncthreads();
    }

#pragma unroll
    for (int m = 0; m < 4; ++m) {
        int i0 = row0 + wr + m * 16 + g * 4;
#pragma unroll
        for (int n = 0; n < 4; ++n) {
            int j = col0 + wc + n * 16 + cl;
            float bv = bias[j];
#pragma unroll
            for (int r = 0; r < 4; ++r)
                out[(size_t)(i0 + r) * C_ + j] = acc[m][n][r] + bv;
        }
    }
}

extern "C" void kernel_launch(void* const* d_in, const int* in_sizes, int n_in,
                              void* d_out, int out_size, void* d_ws, size_t ws_size,
                              hipStream_t stream) {
    (void)in_sizes; (void)n_in; (void)out_size; (void)ws_size;
    const float* x      = (const float*)d_in[0];
    const float* w_attn = (const float*)d_in[1];
    const float* b_attn = (const float*)d_in[2];
    const float* w_proj = (const float*)d_in[3];
    const float* b_proj = (const float*)d_in[4];
    float* out = (float*)d_out;

    char* ws = (char*)d_ws;
    // layout (MB): [0,8) Xb (reused as AO after GEMM1), [8,14) Wt1, [14,16) Wt2,
    //              [16,24) Q, [24,32) K, [32,40) Vt   -- 40 MB total
    unsigned short* Xb  = (unsigned short*)(ws);
    unsigned short* Wt1 = (unsigned short*)(ws + ((size_t)8  << 20));
    unsigned short* Wt2 = (unsigned short*)(ws + ((size_t)14 << 20));
    unsigned short* Qb  = (unsigned short*)(ws + ((size_t)16 << 20));
    unsigned short* Kb  = (unsigned short*)(ws + ((size_t)24 << 20));
    unsigned short* Vt  = (unsigned short*)(ws + ((size_t)32 << 20));
    unsigned short* AO  = Xb;  // Xb dead after gemm_qkv

    cast_x_kernel<<<1024, 256, 0, stream>>>(x, Xb, (M1 * K_) / 4);
    transpose_cast_kernel<<<dim3(N1 / 32, K_ / 32), 256, 0, stream>>>(w_attn, Wt1, K_, N1);
    transpose_cast_kernel<<<dim3(C_ / 32, K_ / 32), 256, 0, stream>>>(w_proj, Wt2, K_, C_);
    gemm_qkv_kernel<<<dim3(M1 / 128, N1 / 128), 256, 0, stream>>>(Xb, Wt1, b_attn, Qb, Kb, Vt);
    attn_kernel<<<dim3(T_ / 64, B_ * H_), 256, 0, stream>>>(Qb, Kb, Vt, AO);
    gemm_proj_kernel<<<dim3(M1 / 128, C_ / 128), 256, 0, stream>>>(AO, Wt2, b_proj, out);
}

// Round 5
// 142.317 us; speedup vs baseline: 2.4223x; 2.4223x over previous
//
#include <hip/hip_runtime.h>
#include <hip/hip_bf16.h>

#define B_ 2
#define T_ 2048
#define C_ 1024
#define H_ 16
#define D_ 64
#define M1 4096
#define N1 3072
#define K_ 1024

typedef __attribute__((ext_vector_type(8))) __bf16 bf16x8;
typedef __attribute__((ext_vector_type(4))) float f32x4;
typedef __attribute__((ext_vector_type(8))) unsigned short ushort8_t;
typedef __attribute__((ext_vector_type(4))) unsigned short ushort4_t;

static __device__ __forceinline__ unsigned short f2bf(float f) {
    unsigned int u = __builtin_bit_cast(unsigned int, f);
    u += 0x7fffu + ((u >> 16) & 1u);
    return (unsigned short)(u >> 16);
}
static __device__ __forceinline__ unsigned short f2bf_hw(float f) {
    return __builtin_bit_cast(unsigned short, (__bf16)f);
}
static __device__ __forceinline__ bf16x8 bload(const unsigned short* p) {
    return __builtin_bit_cast(bf16x8, *(const ushort8_t*)p);
}

// fast exp2 -> v_exp_f32
#if defined(__has_builtin)
#if __has_builtin(__builtin_amdgcn_exp2f)
#define HAVE_EXP2_BUILTIN 1
#endif
#endif
static __device__ __forceinline__ float fexp2(float x) {
#ifdef HAVE_EXP2_BUILTIN
    return __builtin_amdgcn_exp2f(x);
#else
    float r; asm("v_exp_f32 %0, %1" : "=v"(r) : "v"(x)); return r;
#endif
}

// ---- DPP 16-lane reductions (VALU-rate, no LDS pipe) ----
template <int CTRL>
static __device__ __forceinline__ float dpp_mov(float v) {
    return __builtin_bit_cast(float,
        __builtin_amdgcn_update_dpp(0, __builtin_bit_cast(int, v), CTRL, 0xF, 0xF, true));
}
static __device__ __forceinline__ float dpp_fmax16(float v) {
    v = fmaxf(v, dpp_mov<0xB1>(v));
    v = fmaxf(v, dpp_mov<0x4E>(v));
    v = fmaxf(v, dpp_mov<0x141>(v));
    v = fmaxf(v, dpp_mov<0x140>(v));
    return v;
}
static __device__ __forceinline__ float dpp_fadd16(float v) {
    v += dpp_mov<0xB1>(v);
    v += dpp_mov<0x4E>(v);
    v += dpp_mov<0x141>(v);
    v += dpp_mov<0x140>(v);
    return v;
}

// ---- async global->LDS (16B per lane; LDS dest wave-uniform base + lane*16) ----
typedef __attribute__((address_space(1))) const unsigned int gu32;
typedef __attribute__((address_space(3))) unsigned int lu32;
static __device__ __forceinline__ void gld16(const void* g, void* l) {
    __builtin_amdgcn_global_load_lds((gu32*)g, (lu32*)l, 16, 0, 0);
}

#define VMCNT(n) asm volatile("s_waitcnt vmcnt(" #n ")" ::: "memory")
#define LGKM0    asm volatile("s_waitcnt lgkmcnt(0)" ::: "memory")

// ---------------- cast x -> bf16 ----------------
__global__ void cast_x_kernel(const float* __restrict__ in,
                              unsigned short* __restrict__ out, int n4) {
    int idx = blockIdx.x * blockDim.x + threadIdx.x;
    int stride = gridDim.x * blockDim.x;
    for (int i = idx; i < n4; i += stride) {
        float4 v = ((const float4*)in)[i];
        ushort4_t o;
        o.x = f2bf(v.x); o.y = f2bf(v.y); o.z = f2bf(v.z); o.w = f2bf(v.w);
        ((ushort4_t*)out)[i] = o;
    }
}

// ------------- transpose f32[K][N] -> bf16[N][K] -------------
__global__ void transpose_cast_kernel(const float* __restrict__ in,
                                      unsigned short* __restrict__ out,
                                      int K, int N) {
    __shared__ float tile[32][33];
    int tx = threadIdx.x & 31;
    int ty = threadIdx.x >> 5;
    int n0 = blockIdx.x * 32;
    int k0 = blockIdx.y * 32;
#pragma unroll
    for (int rr = 0; rr < 32; rr += 8)
        tile[ty + rr][tx] = in[(size_t)(k0 + ty + rr) * N + n0 + tx];
    __syncthreads();
#pragma unroll
    for (int rr = 0; rr < 32; rr += 8)
        out[(size_t)(n0 + ty + rr) * K + k0 + tx] = f2bf(tile[tx][ty + rr]);
}

// =================== GEMM common body (dbuf LDS via global_load_lds) ===================
// A-tile/B-tile: 128 rows x 32 k (8 KB each), linear LDS (row = 64B -> bank-optimal
// for b128 fragment reads without swizzle). 2 issues of 4KB per tile per step.

#define GEMM_PROLOGUE()                                                                  \
    __shared__ unsigned short As[2][128 * 32];                                           \
    __shared__ unsigned short Bs[2][128 * 32];                                           \
    const int tid = threadIdx.x;                                                         \
    const int lane = tid & 63;                                                           \
    const int wave = tid >> 6;                                                           \
    const int g = lane >> 4, cl = lane & 15;                                             \
    const int wr = (wave >> 1) * 64, wc = (wave & 1) * 64;                               \
    const int row0 = blockIdx.x * 128;                                                   \
    const int col0 = blockIdx.y * 128;                                                   \
    const int srow = tid >> 2;  /* 0..63 */                                              \
    const int sgran = tid & 3;                                                           \
    f32x4 acc[4][4];                                                                     \
    _Pragma("unroll") for (int m = 0; m < 4; ++m)                                        \
        _Pragma("unroll") for (int n = 0; n < 4; ++n)                                    \
            acc[m][n] = (f32x4){0.f, 0.f, 0.f, 0.f};                                     \
    auto stage = [&](int buf, int k0) {                                                  \
        _Pragma("unroll") for (int c = 0; c < 2; ++c) {                                  \
            int r = srow + c * 64;                                                       \
            gld16(A + (size_t)(row0 + r) * K_ + k0 + sgran * 8,                          \
                  (char*)&As[buf][0] + c * 4096 + wave * 1024);                          \
            gld16(Bt + (size_t)(col0 + r) * K_ + k0 + sgran * 8,                         \
                  (char*)&Bs[buf][0] + c * 4096 + wave * 1024);                          \
        }                                                                                \
    };                                                                                   \
    stage(0, 0);                                                                         \
    int buf = 0;                                                                         \
    for (int k0 = 0; k0 < K_; k0 += 32) {                                                \
        if (k0 + 32 < K_) { stage(buf ^ 1, k0 + 32); VMCNT(4); }                         \
        else              { VMCNT(0); }                                                  \
        __builtin_amdgcn_s_barrier();                                                    \
        bf16x8 af[4], bfv[4];                                                            \
        _Pragma("unroll") for (int m = 0; m < 4; ++m)                                    \
            af[m] = bload(&As[buf][(wr + m * 16 + cl) * 32 + g * 8]);                    \
        _Pragma("unroll") for (int n = 0; n < 4; ++n)                                    \
            bfv[n] = bload(&Bs[buf][(wc + n * 16 + cl) * 32 + g * 8]);                   \
        _Pragma("unroll") for (int m = 0; m < 4; ++m)                                    \
            _Pragma("unroll") for (int n = 0; n < 4; ++n)                                \
                acc[m][n] = __builtin_amdgcn_mfma_f32_16x16x32_bf16(                     \
                    af[m], bfv[n], acc[m][n], 0, 0, 0);                                  \
        LGKM0;                                                                           \
        __builtin_amdgcn_s_barrier();                                                    \
        buf ^= 1;                                                                        \
    }

// ---------------- GEMM1: qkv = Xb @ Wt1^T + b ----------------
__global__ __launch_bounds__(256)
void gemm_qkv_kernel(const unsigned short* __restrict__ A,   // [4096][1024] bf16
                     const unsigned short* __restrict__ Bt,  // [3072][1024] bf16
                     const float* __restrict__ bias,         // [3072]
                     unsigned short* __restrict__ Qo,        // [BH][T][D] (pre-scaled)
                     unsigned short* __restrict__ Ko,        // [BH][T][D]
                     unsigned short* __restrict__ Vt)        // [BH][D][T]
{
    GEMM_PROLOGUE()

    const float QSCALE = 0.125f * 1.44269504088896340736f;  // 1/sqrt(D) * log2(e)
#pragma unroll
    for (int m = 0; m < 4; ++m) {
        int i0 = row0 + wr + m * 16 + g * 4;
#pragma unroll
        for (int n = 0; n < 4; ++n) {
            int j = col0 + wc + n * 16 + cl;
            int which = j >> 10;
            int c = j & 1023;
            int h = c >> 6, d = c & 63;
            float bv = bias[j];
#pragma unroll
            for (int r = 0; r < 4; ++r) {
                int i = i0 + r;
                int b = i >> 11, t = i & 2047;
                size_t bh = (size_t)(b * H_ + h);
                float val = acc[m][n][r] + bv;
                if (which == 0) {
                    Qo[(bh * T_ + t) * D_ + d] = f2bf(val * QSCALE);
                } else if (which == 1) {
                    Ko[(bh * T_ + t) * D_ + d] = f2bf(val);
                } else {
                    Vt[(bh * D_ + d) * T_ + t] = f2bf(val);
                }
            }
        }
    }
}

// ---------------- GEMM2: out = AO @ Wt2^T + b (fp32 out) ----------------
__global__ __launch_bounds__(256)
void gemm_proj_kernel(const unsigned short* __restrict__ A,   // [4096][1024] bf16
                      const unsigned short* __restrict__ Bt,  // [1024][1024] bf16
                      const float* __restrict__ bias,         // [1024]
                      float* __restrict__ out)                // [4096][1024] f32
{
    GEMM_PROLOGUE()

#pragma unroll
    for (int m = 0; m < 4; ++m) {
        int i0 = row0 + wr + m * 16 + g * 4;
#pragma unroll
        for (int n = 0; n < 4; ++n) {
            int j = col0 + wc + n * 16 + cl;
            float bv = bias[j];
#pragma unroll
            for (int r = 0; r < 4; ++r)
                out[(size_t)(i0 + r) * C_ + j] = acc[m][n][r] + bv;
        }
    }
}

// ---------------- flash attention (causal, pair-balanced, LDS-staged) ----------------
// grid (16, 32): block p handles q-tiles p and 31-p sequentially -> exactly 33
// kt-steps per block under ANY scheduler. K/V 64x64 tiles staged in LDS via
// global_load_lds, double-buffered, counted vmcnt(4) + raw s_barrier (prefetch
// stays in flight across barriers). K/V LDS XOR-swizzled (granule ^= row&7) via
// pre-swizzled global source; reads apply the same XOR.
__global__ __launch_bounds__(256)
void attn_kernel(const unsigned short* __restrict__ Q,   // [BH][T][D], pre-scaled by log2(e)/8
                 const unsigned short* __restrict__ Kb,  // [BH][T][D]
                 const unsigned short* __restrict__ Vh_, // [BH][D][T]
                 unsigned short* __restrict__ AO)        // [B][T][C] bf16
{
    __shared__ unsigned short Klds[2][64 * 64];   // 16 KB
    __shared__ unsigned short Vlds[2][64 * 64];   // 16 KB
    __shared__ unsigned short Plds[4][16][72];    // per-wave P transpose, 9 KB
    const int pair = blockIdx.x;  // 0..15
    const int bh = blockIdx.y;    // 0..31
    const int b = bh >> 4, h = bh & 15;
    const int tid = threadIdx.x;
    const int lane = tid & 63;
    const int wave = tid >> 6;
    const int g = lane >> 4, cl = lane & 15;

    const unsigned short* Qh = Q + (size_t)bh * T_ * D_;
    const unsigned short* Kh = Kb + (size_t)bh * T_ * D_;
    const unsigned short* Vh = Vh_ + (size_t)bh * D_ * T_;

    const int srow = tid >> 3;  // 0..31
    const int sg   = tid & 7;

    // stage one 64x64 K tile and one 64x64 V tile (8 KB each) into buf.
    // LDS linear dest; global source granule pre-swizzled: lg = sg ^ (row&7).
    auto stage = [&](int buf, int kb) {
#pragma unroll
        for (int c = 0; c < 2; ++c) {
            int r = srow + c * 32;
            int lg = sg ^ (r & 7);
            gld16(Kh + (size_t)(kb + r) * D_ + lg * 8,
                  (char*)&Klds[buf][0] + c * 4096 + wave * 1024);
            gld16(Vh + (size_t)r * T_ + kb + lg * 8,
                  (char*)&Vlds[buf][0] + c * 4096 + wave * 1024);
        }
    };

    for (int half = 0; half < 2; ++half) {
        const int qt = half ? (31 - pair) : pair;
        const int q0 = qt * 64 + wave * 16;

        bf16x8 qf[2];
#pragma unroll
        for (int c2 = 0; c2 < 2; ++c2)
            qf[c2] = bload(Qh + (size_t)(q0 + cl) * D_ + c2 * 32 + g * 8);

        f32x4 oacc[4];
#pragma unroll
        for (int n = 0; n < 4; ++n) oacc[n] = (f32x4){0.f, 0.f, 0.f, 0.f};
        float mrow[4] = {-INFINITY, -INFINITY, -INFINITY, -INFINITY};
        float lrow[4] = {0.f, 0.f, 0.f, 0.f};

        const int nk = qt + 1;
        stage(0, 0);
        int buf = 0;
        for (int kt = 0; kt < nk; ++kt) {
            if (kt + 1 < nk) { stage(buf ^ 1, (kt + 1) * 64); VMCNT(4); }
            else             { VMCNT(0); }
            __builtin_amdgcn_s_barrier();

            const int kb = kt * 64;
            // ---- QK^T from swizzled Klds ----
            f32x4 s0[4];
#pragma unroll
            for (int n = 0; n < 4; ++n) {
                s0[n] = (f32x4){0.f, 0.f, 0.f, 0.f};
#pragma unroll
                for (int c2 = 0; c2 < 2; ++c2) {
                    int pg = (c2 * 4 + g) ^ (cl & 7);
                    bf16x8 kf = bload(&Klds[buf][(n * 16 + cl) * 64 + pg * 8]);
                    s0[n] = __builtin_amdgcn_mfma_f32_16x16x32_bf16(qf[c2], kf, s0[n], 0, 0, 0);
                }
            }
            if (kt == qt) {  // diagonal: causal mask
#pragma unroll
                for (int n = 0; n < 4; ++n) {
                    int tk = kb + n * 16 + cl;
#pragma unroll
                    for (int r = 0; r < 4; ++r) {
                        int tq = q0 + g * 4 + r;
                        if (tk > tq) s0[n][r] = -INFINITY;
                    }
                }
            }
            // ---- online softmax (exp2 domain; scores pre-scaled by log2e) ----
            float p0[4][4];
#pragma unroll
            for (int r = 0; r < 4; ++r) {
                float vmax = s0[0][r];
#pragma unroll
                for (int n = 1; n < 4; ++n) vmax = fmaxf(vmax, s0[n][r]);
                vmax = dpp_fmax16(vmax);
                float mn = fmaxf(mrow[r], vmax);
                float alpha = fexp2(mrow[r] - mn);
                float ps = 0.f;
#pragma unroll
                for (int n = 0; n < 4; ++n) { p0[n][r] = fexp2(s0[n][r] - mn); ps += p0[n][r]; }
                ps = dpp_fadd16(ps);
                lrow[r] = lrow[r] * alpha + ps;
                mrow[r] = mn;
#pragma unroll
                for (int n = 0; n < 4; ++n) oacc[n][r] *= alpha;
            }
            // ---- P transpose via per-wave LDS, then PV from swizzled Vlds ----
#pragma unroll
            for (int n = 0; n < 4; ++n)
#pragma unroll
                for (int r = 0; r < 4; ++r)
                    Plds[wave][g * 4 + r][n * 16 + cl] = f2bf_hw(p0[n][r]);
            bf16x8 pf[2];
#pragma unroll
            for (int c2 = 0; c2 < 2; ++c2)
                pf[c2] = bload(&Plds[wave][cl][c2 * 32 + g * 8]);
#pragma unroll
            for (int n = 0; n < 4; ++n) {
#pragma unroll
                for (int c2 = 0; c2 < 2; ++c2) {
                    int pg = (c2 * 4 + g) ^ (cl & 7);
                    bf16x8 vf = bload(&Vlds[buf][(n * 16 + cl) * 64 + pg * 8]);
                    oacc[n] = __builtin_amdgcn_mfma_f32_16x16x32_bf16(pf[c2], vf, oacc[n], 0, 0, 0);
                }
            }
            LGKM0;
            __builtin_amdgcn_s_barrier();
            buf ^= 1;
        }
        // ---- epilogue ----
#pragma unroll
        for (int r = 0; r < 4; ++r) {
            float inv = 1.f / lrow[r];
            int t = q0 + g * 4 + r;
#pragma unroll
            for (int n = 0; n < 4; ++n)
                AO[((size_t)b * T_ + t) * C_ + h * D_ + n * 16 + cl] =
                    f2bf_hw(oacc[n][r] * inv);
        }
    }
}

extern "C" void kernel_launch(void* const* d_in, const int* in_sizes, int n_in,
                              void* d_out, int out_size, void* d_ws, size_t ws_size,
                              hipStream_t stream) {
    (void)in_sizes; (void)n_in; (void)out_size; (void)ws_size;
    const float* x      = (const float*)d_in[0];
    const float* w_attn = (const float*)d_in[1];
    const float* b_attn = (const float*)d_in[2];
    const float* w_proj = (const float*)d_in[3];
    const float* b_proj = (const float*)d_in[4];
    float* out = (float*)d_out;

    char* ws = (char*)d_ws;
    unsigned short* Xb  = (unsigned short*)(ws);
    unsigned short* Wt1 = (unsigned short*)(ws + ((size_t)8  << 20));
    unsigned short* Wt2 = (unsigned short*)(ws + ((size_t)14 << 20));
    unsigned short* Qb  = (unsigned short*)(ws + ((size_t)16 << 20));
    unsigned short* Kb  = (unsigned short*)(ws + ((size_t)24 << 20));
    unsigned short* Vt  = (unsigned short*)(ws + ((size_t)32 << 20));
    unsigned short* AO  = Xb;  // Xb dead after gemm_qkv

    cast_x_kernel<<<1024, 256, 0, stream>>>(x, Xb, (M1 * K_) / 4);
    transpose_cast_kernel<<<dim3(N1 / 32, K_ / 32), 256, 0, stream>>>(w_attn, Wt1, K_, N1);
    transpose_cast_kernel<<<dim3(C_ / 32, K_ / 32), 256, 0, stream>>>(w_proj, Wt2, K_, C_);
    gemm_qkv_kernel<<<dim3(M1 / 128, N1 / 128), 256, 0, stream>>>(Xb, Wt1, b_attn, Qb, Kb, Vt);
    attn_kernel<<<dim3(16, B_ * H_), 256, 0, stream>>>(Qb, Kb, Vt, AO);
    gemm_proj_kernel<<<dim3(M1 / 128, C_ / 128), 256, 0, stream>>>(AO, Wt2, b_proj, out);
}